// Round 9
// baseline (899.625 us; speedup 1.0000x reference)
//
#include <hip/hip_runtime.h>
#include <math.h>

#define Bn 128
#define Nn 20
#define Hn 128
#define Sn 2
#define STEPS 100
#define NTHREADS 384

__device__ __forceinline__ float wredMaxAll(float v){
  #pragma unroll
  for (int o = 32; o; o >>= 1) v = fmaxf(v, __shfl_xor(v, o));
  return v;
}
__device__ __forceinline__ float wredSumAll(float v){
  #pragma unroll
  for (int o = 32; o; o >>= 1) v += __shfl_xor(v, o);
  return v;
}
// fast transcendentals: v_exp_f32 + v_rcp_f32, branch-free, saturate correctly
__device__ __forceinline__ float frcp_(float x){ return __builtin_amdgcn_rcpf(x); }
__device__ __forceinline__ float ftanh(float x){
  float e = __expf(2.0f * x);          // inf for large x, 0 for very negative -> +/-1 exactly
  return 1.0f - 2.0f * frcp_(e + 1.0f);
}
__device__ __forceinline__ float fsig(float x){ return frcp_(1.0f + __expf(-x)); }

__global__ __launch_bounds__(NTHREADS) void cvrp_ptr_net_kernel(
    const float* __restrict__ adj,   const float* __restrict__ stat,
    const float* __restrict__ dyn,   const float* __restrict__ depot,
    const float* __restrict__ W_adj, const float* __restrict__ b_adj,
    const float* __restrict__ W_stat,const float* __restrict__ b_stat,
    const float* __restrict__ W_dyn, const float* __restrict__ b_dyn,
    const float* __restrict__ W_dec, const float* __restrict__ b_dec,
    const float* __restrict__ Wih,   const float* __restrict__ Whh,
    const float* __restrict__ bih,   const float* __restrict__ bhh,
    const float* __restrict__ attn_v,const float* __restrict__ attn_W,
    const float* __restrict__ ptr_v, const float* __restrict__ ptr_W,
    const float* __restrict__ x0,
    float* __restrict__ out_idx, float* __restrict__ out_logp)
{
  __shared__ float s_attn_pre[Hn][Nn + 1];
  __shared__ float s_ptr_pre[Hn][Nn + 1];
  __shared__ float s_p2s[Hn][Nn + 1];
  __shared__ float s_eA[Hn][Nn + 1];   // prologue only
  __shared__ float s_eS[Hn][Nn + 1];   // prologue only
  __shared__ float s_eD[Hn][Nn + 1];   // prologue only
  __shared__ float s_adj[Nn][Nn];
  __shared__ float s_dep[Nn];
  __shared__ float s_st[Sn][Nn];
  __shared__ float s_dy[Sn][Nn];
  __shared__ float s_wdec0[Hn], s_wdec1[Hn], s_bdec[Hn];
  __shared__ float s_av[Hn], s_pv[Hn];
  __shared__ __align__(16) float s_h[Hn];
  __shared__ float s_a[2 * Hn];
  __shared__ float s_gin[Hn], s_ghn[Hn];
  __shared__ float s_qp[2 * Hn];
  __shared__ float s_sc[Nn];
  __shared__ float s_u[Hn];
  __shared__ float s_p[Nn];
  __shared__ float s_lm[Nn];

  const int b = blockIdx.x;
  const int t = threadIdx.x;

  // ---- stage per-batch inputs & small weights ----
  for (int i = t; i < Nn * Nn; i += NTHREADS) s_adj[i / Nn][i % Nn] = adj[b * Nn * Nn + i];
  if (t < Nn) { float d = depot[b * Nn + t]; s_dep[t] = d; s_lm[t] = logf(d); }
  for (int i = t; i < Sn * Nn; i += NTHREADS) {
    s_st[i / Nn][i % Nn] = stat[b * Sn * Nn + i];
    s_dy[i / Nn][i % Nn] = dyn[b * Sn * Nn + i];
  }
  if (t < Hn) {
    s_wdec0[t] = W_dec[t * Sn]; s_wdec1[t] = W_dec[t * Sn + 1]; s_bdec[t] = b_dec[t];
    s_av[t] = attn_v[t]; s_pv[t] = ptr_v[t];
    s_h[t] = 0.0f;
  }
  __syncthreads();

  // ---- node embeddings ----
  for (int idx = t; idx < Hn * Nn; idx += NTHREADS) {
    int h = idx / Nn, n = idx - h * Nn;
    const float* wa = W_adj + h * (Nn + 1);
    float accA = b_adj[h];
    #pragma unroll
    for (int c = 0; c < Nn; ++c) accA += wa[c] * s_adj[c][n];
    accA += wa[Nn] * s_dep[n];
    s_eA[h][n] = accA;
    s_eS[h][n] = b_stat[h] + W_stat[h * Sn] * s_st[0][n] + W_stat[h * Sn + 1] * s_st[1][n];
    s_eD[h][n] = b_dyn[h]  + W_dyn[h * Sn]  * s_dy[0][n] + W_dyn[h * Sn + 1]  * s_dy[1][n];
  }
  __syncthreads();

  // ---- loop-invariant tables ----
  for (int idx = t; idx < Hn * Nn; idx += NTHREADS) {
    int h = idx / Nn, n = idx - h * Nn;
    const float* aw = attn_W + h * (4 * Hn);
    const float* pw = ptr_W + h * (2 * Hn);
    float acc = 0.f, p1 = 0.f, p2 = 0.f;
    for (int k = 0; k < Hn; ++k) {
      float es = s_eS[k][n];
      acc += aw[k] * s_eA[k][n] + aw[Hn + k] * es + aw[2 * Hn + k] * s_eD[k][n];
      p1  += pw[k] * es;
      p2  += pw[Hn + k] * es;
    }
    s_attn_pre[h][n] = acc; s_ptr_pre[h][n] = p1; s_p2s[h][n] = p2;
  }

  // ---- folded GRU-input coefficients ----
  float g0 = 0.f, g1 = 0.f, gc = 0.f;
  {
    const float* wi = Wih + t * Hn;
    for (int h2 = 0; h2 < Hn; ++h2) {
      float w = wi[h2];
      g0 += w * s_wdec0[h2]; g1 += w * s_wdec1[h2]; gc += w * s_bdec[h2];
    }
    gc += bih[t];
  }
  const float bhh_t = bhh[t];

  // ---- weight registers: Whh row (128) + Wa4 half-row (64) = round-5-proven fit ----
  float wrow[Hn];
  {
    const float4* src = (const float4*)(Whh + t * Hn);
    #pragma unroll
    for (int c = 0; c < Hn / 4; ++c) {
      float4 v = src[c];
      wrow[4 * c] = v.x; wrow[4 * c + 1] = v.y; wrow[4 * c + 2] = v.z; wrow[4 * c + 3] = v.w;
    }
  }
  float wa4h[64];
  {
    int r = t & (Hn - 1), half = (t >> 7) & 1;
    const float4* src = (const float4*)(attn_W + r * 4 * Hn + 3 * Hn + half * 64);
    #pragma unroll
    for (int c = 0; c < 16; ++c) {
      float4 v = src[c];
      wa4h[4 * c] = v.x; wa4h[4 * c + 1] = v.y; wa4h[4 * c + 2] = v.z; wa4h[4 * c + 3] = v.w;
    }
  }
  __syncthreads();

  const int n_s = t >> 4, g_s = t & 15;
  float dec0 = x0[0], dec1 = x0[1];
  float* oi = out_idx + b * STEPS;
  float* ol = out_logp + b * STEPS;

  for (int step = 0; step < STEPS; ++step) {
    // P1: gi (folded) + gh = Whh @ h
    float gi = g0 * dec0 + g1 * dec1 + gc;
    float a0 = bhh_t, a1 = 0.f, a2 = 0.f, a3 = 0.f;
    const float4* h4 = (const float4*)s_h;
    #pragma unroll
    for (int c = 0; c < Hn / 4; ++c) {
      float4 hv = h4[c];
      a0 += wrow[4 * c] * hv.x; a1 += wrow[4 * c + 1] * hv.y;
      a2 += wrow[4 * c + 2] * hv.z; a3 += wrow[4 * c + 3] * hv.w;
    }
    float gh = (a0 + a1) + (a2 + a3);
    if (t < 2 * Hn) s_a[t] = gi + gh;
    else { s_gin[t - 2 * Hn] = gi; s_ghn[t - 2 * Hn] = gh; }
    __syncthreads();                                    // b1

    // P2: GRU elementwise
    if (t < Hn) {
      float rr = fsig(s_a[t]);
      float zz = fsig(s_a[Hn + t]);
      float nn = ftanh(s_gin[t] + rr * s_ghn[t]);
      s_h[t] = (1.0f - zz) * nn + zz * s_h[t];
    }
    __syncthreads();                                    // b2

    // P3: q halves = Wa4 @ h_new
    if (t < 2 * Hn) {
      int half = t >> 7;
      float q0 = 0.f, q1 = 0.f, q2 = 0.f, q3 = 0.f;
      const float4* hh = (const float4*)(s_h + half * 64);
      #pragma unroll
      for (int c = 0; c < 16; ++c) {
        float4 hv = hh[c];
        q0 += wa4h[4 * c] * hv.x; q1 += wa4h[4 * c + 1] * hv.y;
        q2 += wa4h[4 * c + 2] * hv.z; q3 += wa4h[4 * c + 3] * hv.w;
      }
      s_qp[t] = (q0 + q1) + (q2 + q3);
    }
    __syncthreads();                                    // b3

    // P4: attention scores — LDS reads (no register hoist => no spill),
    //     swizzled i-order to spread banks
    if (t < 320) {
      float part = 0.f;
      #pragma unroll
      for (int i = 0; i < 8; ++i) {
        int h2 = g_s * 8 + ((i + g_s) & 7);
        float qv = s_qp[h2] + s_qp[h2 + 128];
        part += s_av[h2] * ftanh(s_attn_pre[h2][n_s] + qv);
      }
      part += __shfl_xor(part, 8);
      part += __shfl_xor(part, 4);
      part += __shfl_xor(part, 2);
      part += __shfl_xor(part, 1);
      if (g_s == 0) s_sc[n_s] = part;
    }
    __syncthreads();                                    // b4

    // P5+P6 fused: in-wave softmax (waves 0-1, redundant) + u = P2S @ attn
    if (t < Hn) {
      int lane = t & 63;
      float v = (lane < Nn) ? s_sc[lane] : -INFINITY;
      float m = wredMaxAll(v);
      float e = (lane < Nn) ? __expf(v - m) : 0.f;
      float ssum = wredSumAll(e);
      float inv = frcp_(ssum);
      float acc = 0.f;
      #pragma unroll
      for (int n = 0; n < Nn; ++n) {
        float an = __shfl(e, n);
        acc += s_p2s[t][n] * an;
      }
      s_u[t] = acc * inv;
    }
    __syncthreads();                                    // b5

    // P7: pointer scores — LDS reads, swizzled
    if (t < 320) {
      float part = 0.f;
      #pragma unroll
      for (int i = 0; i < 8; ++i) {
        int h2 = g_s * 8 + ((i + g_s) & 7);
        part += s_pv[h2] * ftanh(s_ptr_pre[h2][n_s] + s_u[h2]);
      }
      part += __shfl_xor(part, 8);
      part += __shfl_xor(part, 4);
      part += __shfl_xor(part, 2);
      part += __shfl_xor(part, 1);
      if (g_s == 0) s_p[n_s] = part;
    }
    __syncthreads();                                    // b6

    // P8: redundant per-wave argmax (wave-uniform); dec in registers; no barrier
    {
      int lane = t & 63;
      float v = (lane < Nn) ? (s_p[lane] + s_lm[lane]) : -INFINITY;
      float m = wredMaxAll(v);
      unsigned long long mask = __ballot(v == m);
      int amax = __ffsll(mask) - 1;
      dec0 = s_st[0][amax];
      dec1 = s_st[1][amax];
      if (t < 64) {
        float e = (lane < Nn) ? __expf(v - m) : 0.f;
        float ssum = wredSumAll(e);
        if (t == 0) {
          oi[step] = (float)amax;
          ol[step] = -__logf(ssum);
        }
      }
    }
  }
}

extern "C" void kernel_launch(void* const* d_in, const int* in_sizes, int n_in,
                              void* d_out, int out_size, void* d_ws, size_t ws_size,
                              hipStream_t stream) {
  (void)in_sizes; (void)n_in; (void)d_ws; (void)ws_size; (void)out_size;
  const float* adj    = (const float*)d_in[0];
  const float* stat   = (const float*)d_in[1];
  const float* dynp   = (const float*)d_in[2];
  const float* depot  = (const float*)d_in[3];
  const float* W_adj  = (const float*)d_in[4];
  const float* b_adj  = (const float*)d_in[5];
  const float* W_stat = (const float*)d_in[6];
  const float* b_stat = (const float*)d_in[7];
  const float* W_dyn  = (const float*)d_in[8];
  const float* b_dyn  = (const float*)d_in[9];
  const float* W_dec  = (const float*)d_in[10];
  const float* b_dec  = (const float*)d_in[11];
  const float* Wih    = (const float*)d_in[12];
  const float* Whh    = (const float*)d_in[13];
  const float* bih    = (const float*)d_in[14];
  const float* bhh    = (const float*)d_in[15];
  const float* attn_v = (const float*)d_in[16];
  const float* attn_W = (const float*)d_in[17];
  const float* ptr_v  = (const float*)d_in[18];
  const float* ptr_W  = (const float*)d_in[19];
  const float* x0     = (const float*)d_in[20];

  float* out = (float*)d_out;
  hipMemcpyAsync(out, dynp, (size_t)Bn * Sn * Nn * sizeof(float),
                 hipMemcpyDeviceToDevice, stream);
  float* out_idx  = out + Bn * Sn * Nn;
  float* out_logp = out + Bn * Sn * Nn + Bn * STEPS;

  cvrp_ptr_net_kernel<<<Bn, NTHREADS, 0, stream>>>(
      adj, stat, dynp, depot, W_adj, b_adj, W_stat, b_stat, W_dyn, b_dyn,
      W_dec, b_dec, Wih, Whh, bih, bhh, attn_v, attn_W, ptr_v, ptr_W, x0,
      out_idx, out_logp);
}

// Round 10
// 570.920 us; speedup vs baseline: 1.5757x; 1.5757x over previous
//
#include <hip/hip_runtime.h>
#include <math.h>

#define Bn 128
#define Nn 20
#define Hn 128
#define Sn 2
#define STEPS 100
#define NTHREADS 384

__device__ __forceinline__ float wredMaxAll(float v){
  #pragma unroll
  for (int o = 32; o; o >>= 1) v = fmaxf(v, __shfl_xor(v, o));
  return v;
}
__device__ __forceinline__ float wredSumAll(float v){
  #pragma unroll
  for (int o = 32; o; o >>= 1) v += __shfl_xor(v, o);
  return v;
}
// fast transcendentals: v_exp_f32 + v_rcp_f32, branch-free, saturate correctly
__device__ __forceinline__ float frcp_(float x){ return __builtin_amdgcn_rcpf(x); }
__device__ __forceinline__ float ftanh(float x){
  float e = __expf(2.0f * x);          // inf for large x, 0 for very negative -> +/-1 exactly
  return 1.0f - 2.0f * frcp_(e + 1.0f);
}
__device__ __forceinline__ float fsig(float x){ return frcp_(1.0f + __expf(-x)); }

__global__ __launch_bounds__(NTHREADS) void cvrp_ptr_net_kernel(
    const float* __restrict__ adj,   const float* __restrict__ stat,
    const float* __restrict__ dyn,   const float* __restrict__ depot,
    const float* __restrict__ W_adj, const float* __restrict__ b_adj,
    const float* __restrict__ W_stat,const float* __restrict__ b_stat,
    const float* __restrict__ W_dyn, const float* __restrict__ b_dyn,
    const float* __restrict__ W_dec, const float* __restrict__ b_dec,
    const float* __restrict__ Wih,   const float* __restrict__ Whh,
    const float* __restrict__ bih,   const float* __restrict__ bhh,
    const float* __restrict__ attn_v,const float* __restrict__ attn_W,
    const float* __restrict__ ptr_v, const float* __restrict__ ptr_W,
    const float* __restrict__ x0,
    float* __restrict__ out_idx, float* __restrict__ out_logp)
{
  // ---- LDS (~73 KiB) ---- (exact round-5 layout)
  __shared__ float s_attn_pre[Hn][Nn + 1];
  __shared__ float s_ptr_pre[Hn][Nn + 1];
  __shared__ float s_p2s[Hn][Nn + 1];
  __shared__ float s_eA[Hn][Nn + 1];
  __shared__ float s_eS[Hn][Nn + 1];
  __shared__ float s_eD[Hn][Nn + 1];
  __shared__ float s_adj[Nn][Nn];
  __shared__ float s_dep[Nn];
  __shared__ float s_st[Sn][Nn];
  __shared__ float s_dy[Sn][Nn];
  __shared__ float s_wdec0[Hn], s_wdec1[Hn], s_bdec[Hn];
  __shared__ float s_av[Hn], s_pv[Hn];
  __shared__ __align__(16) float s_h[Hn];
  __shared__ float s_a[2 * Hn];
  __shared__ float s_gin[Hn], s_ghn[Hn];
  __shared__ float s_qp[2 * Hn];
  __shared__ float s_sc[Nn];
  __shared__ float s_u[Hn];
  __shared__ float s_p[Nn];
  __shared__ float s_lm[Nn];
  __shared__ float s_dec[2];

  const int b = blockIdx.x;
  const int t = threadIdx.x;

  // ---- stage per-batch inputs & small weights ----
  for (int i = t; i < Nn * Nn; i += NTHREADS) s_adj[i / Nn][i % Nn] = adj[b * Nn * Nn + i];
  if (t < Nn) { float d = depot[b * Nn + t]; s_dep[t] = d; s_lm[t] = logf(d); }
  for (int i = t; i < Sn * Nn; i += NTHREADS) {
    s_st[i / Nn][i % Nn] = stat[b * Sn * Nn + i];
    s_dy[i / Nn][i % Nn] = dyn[b * Sn * Nn + i];
  }
  if (t < Hn) {
    s_wdec0[t] = W_dec[t * Sn]; s_wdec1[t] = W_dec[t * Sn + 1]; s_bdec[t] = b_dec[t];
    s_av[t] = attn_v[t]; s_pv[t] = ptr_v[t];
    s_h[t] = 0.0f;
  }
  if (t == 0) { s_dec[0] = x0[0]; s_dec[1] = x0[1]; }
  __syncthreads();

  // ---- node embeddings ----
  for (int idx = t; idx < Hn * Nn; idx += NTHREADS) {
    int h = idx / Nn, n = idx - h * Nn;
    const float* wa = W_adj + h * (Nn + 1);
    float accA = b_adj[h];
    #pragma unroll
    for (int c = 0; c < Nn; ++c) accA += wa[c] * s_adj[c][n];
    accA += wa[Nn] * s_dep[n];
    s_eA[h][n] = accA;
    s_eS[h][n] = b_stat[h] + W_stat[h * Sn] * s_st[0][n] + W_stat[h * Sn + 1] * s_st[1][n];
    s_eD[h][n] = b_dyn[h]  + W_dyn[h * Sn]  * s_dy[0][n] + W_dyn[h * Sn + 1]  * s_dy[1][n];
  }
  __syncthreads();

  // ---- loop-invariant tables ----
  for (int idx = t; idx < Hn * Nn; idx += NTHREADS) {
    int h = idx / Nn, n = idx - h * Nn;
    const float* aw = attn_W + h * (4 * Hn);
    const float* pw = ptr_W + h * (2 * Hn);
    float acc = 0.f, p1 = 0.f, p2 = 0.f;
    for (int k = 0; k < Hn; ++k) {
      float es = s_eS[k][n];
      acc += aw[k] * s_eA[k][n] + aw[Hn + k] * es + aw[2 * Hn + k] * s_eD[k][n];
      p1  += pw[k] * es;
      p2  += pw[Hn + k] * es;
    }
    s_attn_pre[h][n] = acc; s_ptr_pre[h][n] = p1; s_p2s[h][n] = p2;
  }

  // ---- folded GRU-input coefficients ----
  float g0 = 0.f, g1 = 0.f, gc = 0.f;
  {
    const float* wi = Wih + t * Hn;
    for (int h2 = 0; h2 < Hn; ++h2) {
      float w = wi[h2];
      g0 += w * s_wdec0[h2]; g1 += w * s_wdec1[h2]; gc += w * s_bdec[h2];
    }
    gc += bih[t];
  }
  const float bhh_t = bhh[t];

  // ---- weight registers (round-5-proven fit) ----
  float wrow[Hn];
  {
    const float4* src = (const float4*)(Whh + t * Hn);
    #pragma unroll
    for (int c = 0; c < Hn / 4; ++c) {
      float4 v = src[c];
      wrow[4 * c] = v.x; wrow[4 * c + 1] = v.y; wrow[4 * c + 2] = v.z; wrow[4 * c + 3] = v.w;
    }
  }
  float wa4h[64];
  {
    int r = t & (Hn - 1), half = (t >> 7) & 1;
    const float4* src = (const float4*)(attn_W + r * 4 * Hn + 3 * Hn + half * 64);
    #pragma unroll
    for (int c = 0; c < 16; ++c) {
      float4 v = src[c];
      wa4h[4 * c] = v.x; wa4h[4 * c + 1] = v.y; wa4h[4 * c + 2] = v.z; wa4h[4 * c + 3] = v.w;
    }
  }
  __syncthreads();

  float* oi = out_idx + b * STEPS;
  float* ol = out_logp + b * STEPS;

  for (int step = 0; step < STEPS; ++step) {
    // P1: gi (folded) + gh = Whh @ h
    float dx0 = s_dec[0], dx1 = s_dec[1];
    float gi = g0 * dx0 + g1 * dx1 + gc;
    float a0 = bhh_t, a1 = 0.f, a2 = 0.f, a3 = 0.f;
    const float4* h4 = (const float4*)s_h;
    #pragma unroll
    for (int c = 0; c < Hn / 4; ++c) {
      float4 hv = h4[c];
      a0 += wrow[4 * c] * hv.x; a1 += wrow[4 * c + 1] * hv.y;
      a2 += wrow[4 * c + 2] * hv.z; a3 += wrow[4 * c + 3] * hv.w;
    }
    float gh = (a0 + a1) + (a2 + a3);
    if (t < 2 * Hn) s_a[t] = gi + gh;
    else { s_gin[t - 2 * Hn] = gi; s_ghn[t - 2 * Hn] = gh; }
    __syncthreads();

    // P2: GRU elementwise (fast transcendentals)
    if (t < Hn) {
      float rr = fsig(s_a[t]);
      float zz = fsig(s_a[Hn + t]);
      float nn = ftanh(s_gin[t] + rr * s_ghn[t]);
      s_h[t] = (1.0f - zz) * nn + zz * s_h[t];
    }
    __syncthreads();

    // P3: q partials = Wa4 @ h_new
    if (t < 2 * Hn) {
      int half = t >> 7;
      float q0 = 0.f, q1 = 0.f, q2 = 0.f, q3 = 0.f;
      const float4* hh = (const float4*)(s_h + half * 64);
      #pragma unroll
      for (int c = 0; c < 16; ++c) {
        float4 hv = hh[c];
        q0 += wa4h[4 * c] * hv.x; q1 += wa4h[4 * c + 1] * hv.y;
        q2 += wa4h[4 * c + 2] * hv.z; q3 += wa4h[4 * c + 3] * hv.w;
      }
      s_qp[t] = (q0 + q1) + (q2 + q3);
    }
    __syncthreads();

    // P4: attention scores
    if (t < 320) {
      int n = t >> 4, g = t & 15;
      float part = 0.f;
      #pragma unroll
      for (int i = 0; i < 8; ++i) {
        int h2 = g * 8 + i;
        float qv = s_qp[h2] + s_qp[h2 + 128];
        part += s_av[h2] * ftanh(s_attn_pre[h2][n] + qv);
      }
      part += __shfl_xor(part, 8);
      part += __shfl_xor(part, 4);
      part += __shfl_xor(part, 2);
      part += __shfl_xor(part, 1);
      if (g == 0) s_sc[n] = part;
    }
    __syncthreads();

    // P5: softmax over 20 (wave 0)
    if (t < 64) {
      float v = (t < Nn) ? s_sc[t] : -INFINITY;
      float m = wredMaxAll(v);
      float e = (t < Nn) ? __expf(v - m) : 0.f;
      float ssum = wredSumAll(e);
      if (t < Nn) s_sc[t] = e * frcp_(ssum);
    }
    __syncthreads();

    // P6: u = P2S @ attn
    if (t < Hn) {
      float acc = 0.f;
      #pragma unroll
      for (int n = 0; n < Nn; ++n) acc += s_p2s[t][n] * s_sc[n];
      s_u[t] = acc;
    }
    __syncthreads();

    // P7: pointer scores
    if (t < 320) {
      int n = t >> 4, g = t & 15;
      float part = 0.f;
      #pragma unroll
      for (int i = 0; i < 8; ++i) {
        int h2 = g * 8 + i;
        part += s_pv[h2] * ftanh(s_ptr_pre[h2][n] + s_u[h2]);
      }
      part += __shfl_xor(part, 8);
      part += __shfl_xor(part, 4);
      part += __shfl_xor(part, 2);
      part += __shfl_xor(part, 1);
      if (g == 0) s_p[n] = part;
    }
    __syncthreads();

    // P8: log-softmax + argmax (numpy first-max tie-break) + outputs (wave 0)
    if (t < 64) {
      float v = (t < Nn) ? (s_p[t] + s_lm[t]) : -INFINITY;
      float m = wredMaxAll(v);
      unsigned long long mask = __ballot(v == m);
      int amax = __ffsll(mask) - 1;
      float e = (t < Nn) ? __expf(v - m) : 0.f;
      float ssum = wredSumAll(e);
      if (t == 0) {
        oi[step] = (float)amax;
        ol[step] = -__logf(ssum);
        s_dec[0] = s_st[0][amax];
        s_dec[1] = s_st[1][amax];
      }
    }
    __syncthreads();
  }
}

extern "C" void kernel_launch(void* const* d_in, const int* in_sizes, int n_in,
                              void* d_out, int out_size, void* d_ws, size_t ws_size,
                              hipStream_t stream) {
  (void)in_sizes; (void)n_in; (void)d_ws; (void)ws_size; (void)out_size;
  const float* adj    = (const float*)d_in[0];
  const float* stat   = (const float*)d_in[1];
  const float* dynp   = (const float*)d_in[2];
  const float* depot  = (const float*)d_in[3];
  const float* W_adj  = (const float*)d_in[4];
  const float* b_adj  = (const float*)d_in[5];
  const float* W_stat = (const float*)d_in[6];
  const float* b_stat = (const float*)d_in[7];
  const float* W_dyn  = (const float*)d_in[8];
  const float* b_dyn  = (const float*)d_in[9];
  const float* W_dec  = (const float*)d_in[10];
  const float* b_dec  = (const float*)d_in[11];
  const float* Wih    = (const float*)d_in[12];
  const float* Whh    = (const float*)d_in[13];
  const float* bih    = (const float*)d_in[14];
  const float* bhh    = (const float*)d_in[15];
  const float* attn_v = (const float*)d_in[16];
  const float* attn_W = (const float*)d_in[17];
  const float* ptr_v  = (const float*)d_in[18];
  const float* ptr_W  = (const float*)d_in[19];
  const float* x0     = (const float*)d_in[20];

  float* out = (float*)d_out;
  // output 0: dynamic passthrough (B*S*N floats)
  hipMemcpyAsync(out, dynp, (size_t)Bn * Sn * Nn * sizeof(float),
                 hipMemcpyDeviceToDevice, stream);
  float* out_idx  = out + Bn * Sn * Nn;
  float* out_logp = out + Bn * Sn * Nn + Bn * STEPS;

  cvrp_ptr_net_kernel<<<Bn, NTHREADS, 0, stream>>>(
      adj, stat, dynp, depot, W_adj, b_adj, W_stat, b_stat, W_dyn, b_dyn,
      W_dec, b_dec, Wih, Whh, bih, bhh, attn_v, attn_W, ptr_v, ptr_W, x0,
      out_idx, out_logp);
}